// Round 9
// baseline (113.875 us; speedup 1.0000x reference)
//
#include <hip/hip_runtime.h>

// Problem constants: B=1, T=5, C=64, H=W=32, F=10
#define N_TOK   5120      // T*H*W
#define C_IN    64
#define F_OUT   10
#define FP      12        // padded row stride in ws: [0..9]=data

#define DTILE   40        // denom: Q rows staged per LDS tile
#define MTILE   40        // main: K/V rows staged per LDS tile
#define NCHUNKS 128       // denom n-chunks  -> grid 10*128 = 1280 blocks
#define MCHUNKS 128       // main  m-chunks  -> grid 10*128 = 1280 blocks

// Session ledger: R4 grid-barrier ~250us (stay multi-kernel). R6: atomic
// write-through traffic not binding. R7: removing LDS regresses (VMEM latency
// per j not amortizable). R8: f16-pack + fdot2 cut reads/j 6->4/3->2 (-4.5us).
// R9: the LDS pipe is per-CU (shared by 4 SIMDs) and issue-bound on broadcast
// reads (~5cyc each) -> amortize reads over 2 outputs/thread (register tile).
// Reads per PAIR halve; VALU becomes the binding pipe.

typedef _Float16 h2 __attribute__((ext_vector_type(2)));

__device__ __forceinline__ uint pack2(float a, float b) {
    h2 h = { (_Float16)a, (_Float16)b };
    return __builtin_bit_cast(uint, h);
}
__device__ __forceinline__ h2     as_h2(uint u) { return __builtin_bit_cast(h2, u); }
__device__ __forceinline__ float  as_f(uint u)  { return __builtin_bit_cast(float, u); }
__device__ __forceinline__ uint   as_u(float f) { return __builtin_bit_cast(uint, f); }
__device__ __forceinline__ float2 as_f2(uint a, uint b) {
    return make_float2(as_f(a), as_f(b));
}

// ---------------------------------------------------------------------------
// Kernel A: q/k/v pointwise conv. Thread = one (n, f, arr) output value.
// 600 blocks: arr(3) x f(10) x nblk(20). 64 coalesced loads + 64 FMA each.
// Prologue: blocks [0,200) zero out (51200 f), blocks [200,220) zero dsum.
// ---------------------------------------------------------------------------
__global__ __launch_bounds__(256) void qkv_kernel(
    const float* __restrict__ x1, const float* __restrict__ x2,
    const float* __restrict__ w1, const float* __restrict__ b1,
    const float* __restrict__ w2, const float* __restrict__ b2,
    const float* __restrict__ w3, const float* __restrict__ b3,
    float* __restrict__ Q, float* __restrict__ K, float* __restrict__ V,
    float* __restrict__ out, float* __restrict__ dsum)
{
    if (blockIdx.x < 200)
        out[blockIdx.x * 256 + threadIdx.x] = 0.f;
    else if (blockIdx.x < 220)
        dsum[(blockIdx.x - 200) * 256 + threadIdx.x] = 0.f;

    int arr = blockIdx.x / 200;            // 0=Q, 1=K, 2=V
    int rem = blockIdx.x - arr * 200;
    int f   = rem / 20;
    int nbk = rem - f * 20;
    int n   = nbk * 256 + threadIdx.x;
    int t = n >> 10, p = n & 1023;

    const float* x    = (arr == 1) ? x2 : x1;
    const float* w    = (arr == 0) ? w1 : (arr == 1) ? w2 : w3;
    const float* bias = (arr == 0) ? b1 : (arr == 1) ? b2 : b3;
    float*       dst  = (arr == 0) ? Q  : (arr == 1) ? K  : V;

    const float* xp = x + t * (C_IN * 1024) + p;
    const float* wr = w + f * C_IN;

    float4 wv[16];
#pragma unroll
    for (int i = 0; i < 16; ++i) wv[i] = ((const float4*)wr)[i];

    float acc = 0.f;
#pragma unroll
    for (int i = 0; i < 16; ++i) {
        acc = fmaf(wv[i].x, xp[(4 * i + 0) * 1024], acc);
        acc = fmaf(wv[i].y, xp[(4 * i + 1) * 1024], acc);
        acc = fmaf(wv[i].z, xp[(4 * i + 2) * 1024], acc);
        acc = fmaf(wv[i].w, xp[(4 * i + 3) * 1024], acc);
    }
    dst[n * FP + f] = acc + bias[f];
}

// ---------------------------------------------------------------------------
// Kernel B: softmax denominators. Thread owns TWO m-columns (K packed to
// 2x5 h2 regs) -> the 2 LDS reads per j serve 2 pairs. Q rows staged as
// f16 pairs (5 dw, stride 12 dw). Grid = 10 mTiles x NCHUNKS = 1280 blocks.
// dsum atomics: 2/thread -> 655K total (split-invariant vs R8).
// ---------------------------------------------------------------------------
__global__ __launch_bounds__(256) void denom_kernel(
    const float* __restrict__ Q, const float* __restrict__ K,
    float* __restrict__ dsum, int nclen)
{
    int mTile = blockIdx.x % 10;
    int nc    = blockIdx.x / 10;
    int tid   = threadIdx.x;
    int m0 = mTile * 512 + tid;            // owns m0, m0+256

    h2 kh[2][5];
#pragma unroll
    for (int c = 0; c < 2; ++c) {
        const float* kp = K + (m0 + c * 256) * FP;
        float4 a = ((const float4*)kp)[0];
        float4 b = ((const float4*)kp)[1];
        float2 e = ((const float2*)kp)[4];
        kh[c][0] = h2{ (_Float16)a.x, (_Float16)a.y };
        kh[c][1] = h2{ (_Float16)a.z, (_Float16)a.w };
        kh[c][2] = h2{ (_Float16)b.x, (_Float16)b.y };
        kh[c][3] = h2{ (_Float16)b.z, (_Float16)b.w };
        kh[c][4] = h2{ (_Float16)e.x, (_Float16)e.y };
    }

    __shared__ __align__(16) uint sq[DTILE * 12];   // packed Q rows, 1920 B

    float d[2] = {0.f, 0.f};
    int n0 = nc * nclen;
    for (int base = n0; base < n0 + nclen; base += DTILE) {
        __syncthreads();
        if (tid < DTILE) {                 // thread packs one Q row -> 5 dw
            const float* qp = Q + (base + tid) * FP;
            float4 a = ((const float4*)qp)[0];
            float4 b = ((const float4*)qp)[1];
            float2 e = ((const float2*)qp)[4];
            uint* dst = sq + tid * 12;
            ((uint4*)dst)[0] = make_uint4(pack2(a.x, a.y), pack2(a.z, a.w),
                                          pack2(b.x, b.y), pack2(b.z, b.w));
            dst[4] = pack2(e.x, e.y);
        }
        __syncthreads();
#pragma unroll 4
        for (int j = 0; j < DTILE; ++j) {
            uint4 A  = ((const uint4*)(sq + j * 12))[0];
            uint  a4 = sq[j * 12 + 4];
#pragma unroll
            for (int c = 0; c < 2; ++c) {
                float s = __builtin_amdgcn_fdot2(as_h2(A.x), kh[c][0], 0.f, false);
                s = __builtin_amdgcn_fdot2(as_h2(A.y), kh[c][1], s, false);
                s = __builtin_amdgcn_fdot2(as_h2(A.z), kh[c][2], s, false);
                s = __builtin_amdgcn_fdot2(as_h2(A.w), kh[c][3], s, false);
                s = __builtin_amdgcn_fdot2(as_h2(a4),  kh[c][4], s, false);
                d[c] += __expf(fminf(s, 60.f));
            }
        }
    }
#pragma unroll
    for (int c = 0; c < 2; ++c) atomicAdd(&dsum[m0 + c * 256], d[c]);
}

// ---------------------------------------------------------------------------
// Kernel D: main fused pass. Thread owns TWO rows n (Q packed 2x5 h2 regs)
// -> the 4 LDS reads per j serve 2 pairs. Per-j LDS record (stride 20 dw):
// [0..4]=K f16-pairs, [5]=invw f32, [6..15]=V f32. V-accumulate as float2
// math (v_pk_fma_f32 candidate). Grid = 10 nTiles x MCHUNKS = 1280 blocks.
// Out atomics: 2x10/thread -> 6.55M total (split-invariant vs R8).
// coef(n,m) = w0*relu(s) + w1*sigmoid(s) + exp(s)*invw[m]
// ---------------------------------------------------------------------------
__global__ __launch_bounds__(256) void main_kernel(
    const float* __restrict__ Q, const float* __restrict__ K,
    const float* __restrict__ V, const float* __restrict__ dsum,
    const float* __restrict__ aw, float* __restrict__ out, int mclen)
{
    int nTile = blockIdx.x % 10;
    int mc    = blockIdx.x / 10;
    int tid   = threadIdx.x;
    int nb = nTile * 512 + tid;            // owns nb, nb+256
    float w0 = aw[0], w1v = aw[1];

    h2 qh[2][5];
#pragma unroll
    for (int r = 0; r < 2; ++r) {
        const float* qp = Q + (nb + r * 256) * FP;
        float4 a = ((const float4*)qp)[0];
        float4 b = ((const float4*)qp)[1];
        float2 e = ((const float2*)qp)[4];
        qh[r][0] = h2{ (_Float16)a.x, (_Float16)a.y };
        qh[r][1] = h2{ (_Float16)a.z, (_Float16)a.w };
        qh[r][2] = h2{ (_Float16)b.x, (_Float16)b.y };
        qh[r][3] = h2{ (_Float16)b.z, (_Float16)b.w };
        qh[r][4] = h2{ (_Float16)e.x, (_Float16)e.y };
    }

    float2 acc[2][5];
#pragma unroll
    for (int r = 0; r < 2; ++r)
#pragma unroll
        for (int f = 0; f < 5; ++f) acc[r][f] = make_float2(0.f, 0.f);

    __shared__ __align__(16) uint sm[MTILE * 20];   // packed K/iw/V rows, 3200 B

    int mstart = mc * mclen;
    for (int mbase = mstart; mbase < mstart + mclen; mbase += MTILE) {
        __syncthreads();
        if (tid < MTILE) {                 // thread packs one K/iw/V row -> 16 dw
            int m = mbase + tid;
            const float* kp = K + m * FP;
            float4 ka = ((const float4*)kp)[0];
            float4 kb = ((const float4*)kp)[1];
            float2 kc = ((const float2*)kp)[4];
            const float* vp = V + m * FP;
            float4 va = ((const float4*)vp)[0];
            float4 vb = ((const float4*)vp)[1];
            float2 vc = ((const float2*)vp)[4];
            float iw = w0 * __builtin_amdgcn_rcpf(dsum[m]);
            uint* dst = sm + tid * 20;
            ((uint4*)dst)[0] = make_uint4(pack2(ka.x, ka.y), pack2(ka.z, ka.w),
                                          pack2(kb.x, kb.y), pack2(kb.z, kb.w));
            ((uint4*)dst)[1] = make_uint4(pack2(kc.x, kc.y), as_u(iw),
                                          as_u(va.x), as_u(va.y));
            ((uint4*)dst)[2] = make_uint4(as_u(va.z), as_u(va.w),
                                          as_u(vb.x), as_u(vb.y));
            ((uint4*)dst)[3] = make_uint4(as_u(vb.z), as_u(vb.w),
                                          as_u(vc.x), as_u(vc.y));
        }
        __syncthreads();

#pragma unroll 4
        for (int j = 0; j < MTILE; ++j) {
            const uint4* rp = (const uint4*)(sm + j * 20);
            uint4 A = rp[0], B = rp[1], C = rp[2], D = rp[3];
            float iw = as_f(B.y);
            float2 v01 = as_f2(B.z, B.w), v23 = as_f2(C.x, C.y),
                   v45 = as_f2(C.z, C.w), v67 = as_f2(D.x, D.y),
                   v89 = as_f2(D.z, D.w);

#pragma unroll
            for (int r = 0; r < 2; ++r) {
                float s = __builtin_amdgcn_fdot2(qh[r][0], as_h2(A.x), 0.f, false);
                s = __builtin_amdgcn_fdot2(qh[r][1], as_h2(A.y), s, false);
                s = __builtin_amdgcn_fdot2(qh[r][2], as_h2(A.z), s, false);
                s = __builtin_amdgcn_fdot2(qh[r][3], as_h2(A.w), s, false);
                s = __builtin_amdgcn_fdot2(qh[r][4], as_h2(B.x), s, false);

                float rl = fmaxf(s, 0.f);
                float e  = __expf(fminf(s, 60.f));
                float sg = e * __builtin_amdgcn_rcpf(1.f + e);
                float cf = fmaf(e, iw, fmaf(w1v, sg, w0 * rl));
                float2 cf2 = make_float2(cf, cf);

                acc[r][0] += cf2 * v01;
                acc[r][1] += cf2 * v23;
                acc[r][2] += cf2 * v45;
                acc[r][3] += cf2 * v67;
                acc[r][4] += cf2 * v89;
            }
        }
    }

    // direct transposed accumulation into out[((t*10+f)<<10) + p]
#pragma unroll
    for (int r = 0; r < 2; ++r) {
        int n = nb + r * 256;
        int t = n >> 10, p = n & 1023;
        float* obase = out + ((t * F_OUT) << 10) + p;
#pragma unroll
        for (int f = 0; f < 5; ++f) {
            atomicAdd(obase + ((2 * f)     << 10), acc[r][f].x);
            atomicAdd(obase + ((2 * f + 1) << 10), acc[r][f].y);
        }
    }
}

// ---------------------------------------------------------------------------
extern "C" void kernel_launch(void* const* d_in, const int* in_sizes, int n_in,
                              void* d_out, int out_size, void* d_ws, size_t ws_size,
                              hipStream_t stream)
{
    const float* in1 = (const float*)d_in[0];
    const float* in2 = (const float*)d_in[1];
    const float* aw  = (const float*)d_in[2];
    const float* w1  = (const float*)d_in[3];
    const float* b1  = (const float*)d_in[4];
    const float* w2  = (const float*)d_in[5];
    const float* b2  = (const float*)d_in[6];
    const float* w3  = (const float*)d_in[7];
    const float* b3  = (const float*)d_in[8];
    float* out = (float*)d_out;

    // workspace: Q/K/V padded rows + dsum (~758 KB)
    float* ws   = (float*)d_ws;
    float* Q    = ws;                        // N*FP
    float* K    = Q + N_TOK * FP;
    float* V    = K + N_TOK * FP;
    float* dsum = V + N_TOK * FP;            // N

    int nclen = N_TOK / NCHUNKS;   // 40 (single DTILE iter per block)
    int mclen = N_TOK / MCHUNKS;   // 40 (single MTILE iter per block)

    qkv_kernel<<<600, 256, 0, stream>>>(in1, in2, w1, b1, w2, b2, w3, b3,
                                        Q, K, V, out, dsum);
    denom_kernel<<<10 * NCHUNKS, 256, 0, stream>>>(Q, K, dsum, nclen);
    main_kernel<<<10 * MCHUNKS, 256, 0, stream>>>(Q, K, V, dsum, aw, out, mclen);
}